// Round 15
// baseline (209.455 us; speedup 1.0000x reference)
//
#include <hip/hip_runtime.h>

#define N_NODES 100000
#define N_EDGES 1600000
#define D 64
#define NB 131                 // nodes per bucket
#define NBUCKETS 764           // ceil(100000/131)
#define PCHUNK 4096            // edges per partition chunk (391 blocks)
#define NCHUNK 391             // ceil(N_EDGES / PCHUNK)
#define PBLK 1024
#define NCH_N 98               // ceil(N_NODES / 1024) for node-sort chunks

typedef unsigned int u32;
typedef unsigned short u16;
typedef _Float16 f16;
typedef f16 f16x8 __attribute__((ext_vector_type(8)));
typedef float f32x4 __attribute__((ext_vector_type(4)));

// ---------------- pass 1: per-chunk bucket histogram (LDS atomics only) ----------------
__global__ __launch_bounds__(PBLK) void hist_kernel(const int* __restrict__ dst,
                                                    int* __restrict__ hist) {
    __shared__ int hcnt[NBUCKETS];
    int t = threadIdx.x;
    int c0 = blockIdx.x * PCHUNK;
    int nloc = min(PCHUNK, N_EDGES - c0);
    for (int i = t; i < NBUCKETS; i += PBLK) hcnt[i] = 0;
    __syncthreads();
    for (int i = t; i < nloc; i += PBLK) atomicAdd(&hcnt[dst[c0 + i] / NB], 1);
    __syncthreads();
    for (int i = t; i < NBUCKETS; i += PBLK) hist[blockIdx.x * NBUCKETS + i] = hcnt[i];
}

// ---------------- pass 2a: per-bucket totals (parallel column sums) ----------------
__global__ void colsum_kernel(const int* __restrict__ hist, int* __restrict__ btot) {
    int t = blockIdx.x * blockDim.x + threadIdx.x;
    if (t < NBUCKETS) {
        int s = 0;
        for (int c = 0; c < NCHUNK; ++c) s += hist[c * NBUCKETS + t];
        btot[t] = s;
    }
}

// ---------------- pass 2b: scan 764 totals -> bptr[765] ----------------
__global__ __launch_bounds__(1024) void bscan_kernel(const int* __restrict__ btot,
                                                     int* __restrict__ bptr) {
    __shared__ int s[1024];
    int t = threadIdx.x;
    int v = (t < NBUCKETS) ? btot[t] : 0;
    s[t] = v;
    __syncthreads();
    for (int off = 1; off < 1024; off <<= 1) {
        int a = (t >= off) ? s[t - off] : 0;
        __syncthreads();
        s[t] += a;
        __syncthreads();
    }
    if (t < NBUCKETS) bptr[t] = s[t] - v;   // exclusive
    if (t == NBUCKETS - 1) bptr[NBUCKETS] = s[t];
}

// ---------------- pass 2c: rewrite hist as per-(chunk,bucket) base offsets ----------------
__global__ void rebase_kernel(int* __restrict__ hist, const int* __restrict__ bptr) {
    int t = blockIdx.x * blockDim.x + threadIdx.x;
    if (t < NBUCKETS) {
        int run = bptr[t];
        for (int c = 0; c < NCHUNK; ++c) {
            int v = hist[c * NBUCKETS + t];
            hist[c * NBUCKETS + t] = run;
            run += v;
        }
    }
}

// ---------------- pass 3: partition (zero global atomics) ----------------
__global__ __launch_bounds__(PBLK) void part_kernel(const int* __restrict__ src,
                                                    const int* __restrict__ dst,
                                                    const int* __restrict__ cbase,
                                                    u32* __restrict__ pairs) {
    __shared__ int hcur[NBUCKETS];
    __shared__ int hb[NBUCKETS];
    int t = threadIdx.x;
    int c0 = blockIdx.x * PCHUNK;
    int nloc = min(PCHUNK, N_EDGES - c0);
    for (int i = t; i < NBUCKETS; i += PBLK) {
        hcur[i] = 0;
        hb[i] = cbase[blockIdx.x * NBUCKETS + i];
    }
    __syncthreads();
    for (int i = t; i < nloc; i += PBLK) {
        int s = src[c0 + i];
        int d = dst[c0 + i];
        int b = d / NB;
        int r = atomicAdd(&hcur[b], 1);
        pairs[hb[b] + r] = ((u32)(d - b * NB) << 24) | (u32)s;
    }
}

// ---------------- per-bucket local CSR: histogram -> scan -> fill ----------------
__global__ __launch_bounds__(256) void local_csr_kernel(
    const u32* __restrict__ pairs, const int* __restrict__ bptr,
    int* __restrict__ row_ptr, int* __restrict__ cnt, float* __restrict__ inv,
    int* __restrict__ csr_src)
{
    __shared__ int lcnt[NB];
    __shared__ int lofs[NB];
    __shared__ int s[256];

    int t = threadIdx.x, b = blockIdx.x;
    int e0 = bptr[b], e1 = bptr[b + 1];
    int nb0 = b * NB;

    for (int i = t; i < NB; i += 256) lcnt[i] = 0;
    __syncthreads();
    for (int e = e0 + t; e < e1; e += 256) atomicAdd(&lcnt[pairs[e] >> 24], 1);
    __syncthreads();

    int v = (t < NB) ? lcnt[t] : 0;
    s[t] = v;
    __syncthreads();
    for (int off = 1; off < 256; off <<= 1) {
        int a = (t >= off) ? s[t - off] : 0;
        __syncthreads();
        s[t] += a;
        __syncthreads();
    }
    if (t < NB) {
        int node = nb0 + t;
        if (node < N_NODES) {
            int excl = s[t] - v;
            lofs[t] = excl;
            row_ptr[node] = e0 + excl;
            cnt[node] = v;
            inv[node] = 1.0f / fmaxf((float)v, 1.0f);
        }
        lcnt[t] = 0;   // reuse as fill cursor
    }
    __syncthreads();
    for (int e = e0 + t; e < e1; e += 256) {
        u32 p = pairs[e];
        int dl = (int)(p >> 24);
        int pos = atomicAdd(&lcnt[dl], 1);
        csr_src[e0 + lofs[dl] + pos] = (int)(p & 0xFFFFFFu);
    }
}

// ---------------- node degree-sort (descending), deterministic two-level ----------------
// 64 degree bins, bin = 63 - min(deg,63). perm[pos] = node, sorted by bin.
__global__ __launch_bounds__(1024) void nhist_kernel(const int* __restrict__ cnt,
                                                     int* __restrict__ nhist) {
    __shared__ int h[64];
    int t = threadIdx.x;
    if (t < 64) h[t] = 0;
    __syncthreads();
    int i = blockIdx.x * 1024 + t;
    if (i < N_NODES) atomicAdd(&h[63 - min(cnt[i], 63)], 1);
    __syncthreads();
    if (t < 64) nhist[blockIdx.x * 64 + t] = h[t];
}

__global__ __launch_bounds__(64) void nmid_kernel(int* __restrict__ nhist) {
    __shared__ int s[64];
    int t = threadIdx.x;     // bin
    int tot = 0;
    for (int c = 0; c < NCH_N; ++c) tot += nhist[c * 64 + t];
    s[t] = tot;
    __syncthreads();
    for (int off = 1; off < 64; off <<= 1) {
        int a = (t >= off) ? s[t - off] : 0;
        __syncthreads();
        s[t] += a;
        __syncthreads();
    }
    int run = s[t] - tot;    // exclusive prefix
    for (int c = 0; c < NCH_N; ++c) {
        int v = nhist[c * 64 + t];
        nhist[c * 64 + t] = run;
        run += v;
    }
}

__global__ __launch_bounds__(1024) void nscatter_kernel(const int* __restrict__ cnt,
                                                        const int* __restrict__ nhist,
                                                        int* __restrict__ perm) {
    __shared__ int cur[64];
    int t = threadIdx.x;
    if (t < 64) cur[t] = nhist[blockIdx.x * 64 + t];
    __syncthreads();
    int i = blockIdx.x * 1024 + t;
    if (i < N_NODES) {
        int bin = 63 - min(cnt[i], 63);
        int pos = atomicAdd(&cur[bin], 1);
        perm[pos] = i;
    }
}

// ---------------- f32 -> f16 conversion (4 elems/thread) ----------------
__global__ void tof16_kernel(const float* __restrict__ in, u16* __restrict__ outh, int n4) {
    int i = blockIdx.x * blockDim.x + threadIdx.x;
    if (i < n4) {
        float4 v = reinterpret_cast<const float4*>(in)[i];
        union { f16 h[4]; uint2 u; } cv;
        cv.h[0] = (f16)v.x; cv.h[1] = (f16)v.y; cv.h[2] = (f16)v.z; cv.h[3] = (f16)v.w;
        reinterpret_cast<uint2*>(outh)[i] = cv.u;
    }
}

// ---------------- precompute MFMA B-fragments for all 3 layers (verified layout) -----------
__global__ void prep_bfrag(const float* __restrict__ Wl0, const float* __restrict__ Wr0,
                           const float* __restrict__ Wl1, const float* __restrict__ Wr1,
                           const float* __restrict__ Wl2, const float* __restrict__ Wr2,
                           uint4* __restrict__ Bfrag) {
    int idx = blockIdx.x * blockDim.x + threadIdx.x;
    if (idx >= 3 * 16 * 64) return;
    int layer = idx >> 10, r = idx & 1023, f = r >> 6, l = r & 63;
    const float* Wl = layer == 0 ? Wl0 : layer == 1 ? Wl1 : Wl2;
    const float* Wr = layer == 0 ? Wr0 : layer == 1 ? Wr1 : Wr2;
    int ktg = f >> 2, nt = f & 3;
    const float* W = (ktg & 2) ? Wr : Wl;
    int o = nt * 16 + (l & 15);
    int k = (ktg & 1) * 32 + (l >> 4) * 8;
    const float* s = W + o * 64 + k;
    float4 v0 = *reinterpret_cast<const float4*>(s);
    float4 v1 = *reinterpret_cast<const float4*>(s + 4);
    union { f16x8 h; uint4 u; } cv;
    cv.h[0] = (f16)v0.x; cv.h[1] = (f16)v0.y; cv.h[2] = (f16)v0.z; cv.h[3] = (f16)v0.w;
    cv.h[4] = (f16)v1.x; cv.h[5] = (f16)v1.y; cv.h[6] = (f16)v1.z; cv.h[7] = (f16)v1.w;
    Bfrag[idx] = cv.u;
}

__device__ __forceinline__ void add8(float* va, uint4 r) {
    union { uint4 u; f16x8 h; } cv; cv.u = r;
    #pragma unroll
    for (int e = 0; e < 8; ++e) va[e] += (float)cv.h[e];
}

// ---------------- fused SAGE layer (MFMA, barrier-free, 8 nodes/wave, degree-sorted) -------
// R13 structure (the measured optimum of the nodes/wave sweep: 16->41.2, 8->39.8,
// 4->47.1 us) + degree-sorted perm: wave w handles perm[base..base+7] — 8 nodes of
// ~equal degree, so wave time = max over subgroup chains ~= mean (was E[max of 8
// Poisson(16)] ~ 1.5x mean). Descending order -> heavy blocks scheduled first.
__global__ __launch_bounds__(256, 8) void sage_layer(
    const u16* __restrict__ hh,        // f16 features [N][64]
    const int* __restrict__ perm,
    const int* __restrict__ row_ptr, const int* __restrict__ cnt,
    const int* __restrict__ csr_src, const float* __restrict__ inv,
    const uint4* __restrict__ Bfrag,   // 16 fragments x 64 lanes (this layer)
    const float* __restrict__ bvec,
    float* __restrict__ outf,          // f32 output (nullptr to skip)
    u16* __restrict__ outh,            // f16 output (nullptr to skip)
    int relu)
{
    __shared__ u16 Atile[4][8][128];       // per-wave swizzled A, rows 0..7
    __shared__ int pn[4][8];               // per-wave node ids (wave-private, no barrier)

    int t = threadIdx.x;
    int w    = t >> 6;
    int lane = t & 63;
    int j8   = lane & 7;    // channel octet within row
    int sg   = lane >> 3;   // subgroup 0..7 = node slot within wave
    const uint4* rows = reinterpret_cast<const uint4*>(hh);   // 8 x uint4 per node

    int base = blockIdx.x * 32 + w * 8;    // grid covers N exactly (3125*32)

    float bias[4];
    #pragma unroll
    for (int nt = 0; nt < 4; ++nt) bias[nt] = bvec[nt * 16 + (lane & 15)];

    // ---- gather: subgroup sg accumulates node perm[base+sg] ----
    {
        int node = perm[base + sg];
        if (j8 == 0) pn[w][sg] = node;
        uint4 selfrow = rows[node * 8 + j8];       // in flight during gather
        int s0 = row_ptr[node];
        int c  = cnt[node];
        float va[8] = {0.f,0.f,0.f,0.f,0.f,0.f,0.f,0.f};
        int j = 0;
        for (; j + 4 <= c; j += 4) {
            int i0 = csr_src[s0 + j];
            int i1 = csr_src[s0 + j + 1];
            int i2 = csr_src[s0 + j + 2];
            int i3 = csr_src[s0 + j + 3];
            uint4 r0 = rows[i0 * 8 + j8];
            uint4 r1 = rows[i1 * 8 + j8];
            uint4 r2 = rows[i2 * 8 + j8];
            uint4 r3 = rows[i3 * 8 + j8];
            add8(va, r0); add8(va, r1); add8(va, r2); add8(va, r3);
        }
        for (; j < c; ++j) {
            add8(va, rows[csr_src[s0 + j] * 8 + j8]);
        }
        float sc = inv[node];
        union { f16x8 h; uint4 u; } mv;
        #pragma unroll
        for (int e = 0; e < 8; ++e) mv.h[e] = (f16)(va[e] * sc);
        int chunk = j8 ^ sg;
        *reinterpret_cast<uint4*>(&Atile[w][sg][chunk * 8]) = mv.u;         // mean, k 0..63
        *reinterpret_cast<uint4*>(&Atile[w][sg][64 + chunk * 8]) = selfrow; // self, k 64..127
    }

    // ---- fragment reads + 16 MFMAs (B straight from global) ----
    f32x4 acc[4] = {};
    int row = lane & 15, kg = lane >> 4;
    int rowc = row & 7;                // rows 8..15 alias row&7 (their C rows unused)
    #pragma unroll
    for (int ktg = 0; ktg < 4; ++ktg) {
        int idx16 = ktg * 4 + kg;
        int swz = (idx16 & 8) | ((idx16 & 7) ^ (rowc & 7));
        uint4 a = *reinterpret_cast<const uint4*>(&Atile[w][rowc][swz * 8]);
        union { uint4 u; f16x8 h; } av; av.u = a;
        #pragma unroll
        for (int nt = 0; nt < 4; ++nt) {
            union { uint4 u; f16x8 h; } bv; bv.u = Bfrag[(ktg * 4 + nt) * 64 + lane];
            acc[nt] = __builtin_amdgcn_mfma_f32_16x16x32_f16(av.h, bv.h, acc[nt], 0, 0, 0);
        }
    }

    // ---- epilogue: bias (+ReLU), stores. C: col=lane&15, row=(lane>>4)*4+reg ----
    // Only C rows 0..7 (kg<2) are real node slots.
    #pragma unroll
    for (int nt = 0; nt < 4; ++nt) {
        int o = nt * 16 + (lane & 15);
        #pragma unroll
        for (int r = 0; r < 4; ++r) {
            int n = kg * 4 + r;
            if (n < 8) {
                int node = pn[w][n];
                float vout = acc[nt][r] + bias[nt];
                if (relu) vout = fmaxf(vout, 0.f);
                if (outf) outf[node * 64 + o] = vout;
                if (outh) {
                    union { f16 h; u16 u; } cv; cv.h = (f16)vout;
                    outh[node * 64 + o] = cv.u;
                }
            }
        }
    }
}

extern "C" void kernel_launch(void* const* d_in, const int* in_sizes, int n_in,
                              void* d_out, int out_size, void* d_ws, size_t ws_size,
                              hipStream_t stream) {
    const float* x   = (const float*)d_in[0];
    const int*   ei  = (const int*)d_in[1];
    const int*   src = ei;
    const int*   dst = ei + N_EDGES;
    const float* Wl0 = (const float*)d_in[2];
    const float* Wr0 = (const float*)d_in[3];
    const float* b0  = (const float*)d_in[4];
    const float* Wl1 = (const float*)d_in[5];
    const float* Wr1 = (const float*)d_in[6];
    const float* b1  = (const float*)d_in[7];
    const float* Wl2 = (const float*)d_in[8];
    const float* Wr2 = (const float*)d_in[9];
    const float* b2  = (const float*)d_in[10];
    float* out = (float*)d_out;

    // ---- workspace layout (256B-aligned regions) ----
    char* p = (char*)d_ws;
    auto take = [&](size_t bytes) { char* r = p; p += (bytes + 255) & ~(size_t)255; return r; };
    int*   hist    = (int*)take((size_t)NCHUNK * NBUCKETS * 4);
    int*   btot    = (int*)take((size_t)NBUCKETS * 4);
    int*   bptr    = (int*)take((size_t)(NBUCKETS + 1) * 4);
    u32*   pairs   = (u32*)take((size_t)N_EDGES * 4);
    int*   csr_src = (int*)take((size_t)N_EDGES * 4);
    int*   row_ptr = (int*)take((size_t)N_NODES * 4);
    int*   cnt     = (int*)take((size_t)N_NODES * 4);
    float* inv     = (float*)take((size_t)N_NODES * 4);
    int*   nhist   = (int*)take((size_t)NCH_N * 64 * 4);
    int*   perm    = (int*)take((size_t)N_NODES * 4);
    uint4* Bfrag   = (uint4*)take((size_t)3 * 16 * 64 * 16);
    u16*   xh      = (u16*)take((size_t)N_NODES * D * 2);
    u16*   h0h     = (u16*)take((size_t)N_NODES * D * 2);
    u16*   h1h     = (u16*)take((size_t)N_NODES * D * 2);

    const int BLK = 256;
    const int conv_grid  = (N_NODES * D / 4 + BLK - 1) / BLK;
    const int layer_grid = (N_NODES + 31) / 32;    // 32 nodes per block (8/wave)
    const int bgrid      = (NBUCKETS + BLK - 1) / BLK;

    // ---- deterministic bucketed partition + CSR (zero global atomics) ----
    hist_kernel<<<NCHUNK, PBLK, 0, stream>>>(dst, hist);
    colsum_kernel<<<bgrid, BLK, 0, stream>>>(hist, btot);
    bscan_kernel<<<1, 1024, 0, stream>>>(btot, bptr);
    rebase_kernel<<<bgrid, BLK, 0, stream>>>(hist, bptr);
    part_kernel<<<NCHUNK, PBLK, 0, stream>>>(src, dst, hist, pairs);
    local_csr_kernel<<<NBUCKETS, BLK, 0, stream>>>(pairs, bptr, row_ptr, cnt, inv, csr_src);

    // ---- degree-sorted node permutation (needs cnt) ----
    nhist_kernel<<<NCH_N, 1024, 0, stream>>>(cnt, nhist);
    nmid_kernel<<<1, 64, 0, stream>>>(nhist);
    nscatter_kernel<<<NCH_N, 1024, 0, stream>>>(cnt, nhist, perm);

    tof16_kernel<<<conv_grid, BLK, 0, stream>>>(x, xh, N_NODES * D / 4);
    prep_bfrag<<<(3 * 1024 + BLK - 1) / BLK, BLK, 0, stream>>>(Wl0, Wr0, Wl1, Wr1, Wl2, Wr2, Bfrag);

    // ---- 3 fused layers (intermediates are f16-only) ----
    sage_layer<<<layer_grid, BLK, 0, stream>>>(xh,  perm, row_ptr, cnt, csr_src, inv, Bfrag,        b0, nullptr, h0h, 1);
    sage_layer<<<layer_grid, BLK, 0, stream>>>(h0h, perm, row_ptr, cnt, csr_src, inv, Bfrag + 1024, b1, nullptr, h1h, 1);
    sage_layer<<<layer_grid, BLK, 0, stream>>>(h1h, perm, row_ptr, cnt, csr_src, inv, Bfrag + 2048, b2, out, nullptr, 0);
}

// Round 16
// 170.219 us; speedup vs baseline: 1.2305x; 1.2305x over previous
//
#include <hip/hip_runtime.h>

#define N_NODES 100000
#define N_EDGES 1600000
#define D 64
#define NB 131                 // nodes per bucket
#define NBUCKETS 764           // ceil(100000/131)
#define PCHUNK 8192            // edges per partition chunk (196 blocks: parallelism > coalescing)
#define NCHUNK 196             // ceil(N_EDGES / PCHUNK)
#define PBLK 1024

typedef unsigned int u32;
typedef unsigned short u16;
typedef _Float16 f16;
typedef f16 f16x8 __attribute__((ext_vector_type(8)));
typedef float f32x4 __attribute__((ext_vector_type(4)));

// ---------------- pass 1: per-chunk bucket histogram (LDS atomics only) ----------------
__global__ __launch_bounds__(PBLK) void hist_kernel(const int* __restrict__ dst,
                                                    int* __restrict__ hist) {
    __shared__ int hcnt[NBUCKETS];
    int t = threadIdx.x;
    int c0 = blockIdx.x * PCHUNK;
    int nloc = min(PCHUNK, N_EDGES - c0);
    for (int i = t; i < NBUCKETS; i += PBLK) hcnt[i] = 0;
    __syncthreads();
    for (int i = t; i < nloc; i += PBLK) atomicAdd(&hcnt[dst[c0 + i] / NB], 1);
    __syncthreads();
    for (int i = t; i < NBUCKETS; i += PBLK) hist[blockIdx.x * NBUCKETS + i] = hcnt[i];
}

// ---------------- pass 2a: per-bucket totals (parallel column sums) ----------------
__global__ void colsum_kernel(const int* __restrict__ hist, int* __restrict__ btot) {
    int t = blockIdx.x * blockDim.x + threadIdx.x;
    if (t < NBUCKETS) {
        int s = 0;
        for (int c = 0; c < NCHUNK; ++c) s += hist[c * NBUCKETS + t];
        btot[t] = s;
    }
}

// ---------------- pass 2b: scan 764 totals -> bptr[765] ----------------
__global__ __launch_bounds__(1024) void bscan_kernel(const int* __restrict__ btot,
                                                     int* __restrict__ bptr) {
    __shared__ int s[1024];
    int t = threadIdx.x;
    int v = (t < NBUCKETS) ? btot[t] : 0;
    s[t] = v;
    __syncthreads();
    for (int off = 1; off < 1024; off <<= 1) {
        int a = (t >= off) ? s[t - off] : 0;
        __syncthreads();
        s[t] += a;
        __syncthreads();
    }
    if (t < NBUCKETS) bptr[t] = s[t] - v;   // exclusive
    if (t == NBUCKETS - 1) bptr[NBUCKETS] = s[t];
}

// ---------------- pass 2c: rewrite hist as per-(chunk,bucket) base offsets ----------------
__global__ void rebase_kernel(int* __restrict__ hist, const int* __restrict__ bptr) {
    int t = blockIdx.x * blockDim.x + threadIdx.x;
    if (t < NBUCKETS) {
        int run = bptr[t];
        for (int c = 0; c < NCHUNK; ++c) {
            int v = hist[c * NBUCKETS + t];
            hist[c * NBUCKETS + t] = run;
            run += v;
        }
    }
}

// ---------------- pass 3: partition (zero global atomics) ----------------
__global__ __launch_bounds__(PBLK) void part_kernel(const int* __restrict__ src,
                                                    const int* __restrict__ dst,
                                                    const int* __restrict__ cbase,
                                                    u32* __restrict__ pairs) {
    __shared__ int hcur[NBUCKETS];
    __shared__ int hb[NBUCKETS];
    int t = threadIdx.x;
    int c0 = blockIdx.x * PCHUNK;
    int nloc = min(PCHUNK, N_EDGES - c0);
    for (int i = t; i < NBUCKETS; i += PBLK) {
        hcur[i] = 0;
        hb[i] = cbase[blockIdx.x * NBUCKETS + i];
    }
    __syncthreads();
    for (int i = t; i < nloc; i += PBLK) {
        int s = src[c0 + i];
        int d = dst[c0 + i];
        int b = d / NB;
        int r = atomicAdd(&hcur[b], 1);
        pairs[hb[b] + r] = ((u32)(d - b * NB) << 24) | (u32)s;
    }
}

// ---------------- per-bucket local CSR: histogram -> scan -> fill ----------------
__global__ __launch_bounds__(256) void local_csr_kernel(
    const u32* __restrict__ pairs, const int* __restrict__ bptr,
    int* __restrict__ row_ptr, int* __restrict__ cnt, float* __restrict__ inv,
    int* __restrict__ csr_src)
{
    __shared__ int lcnt[NB];
    __shared__ int lofs[NB];
    __shared__ int s[256];

    int t = threadIdx.x, b = blockIdx.x;
    int e0 = bptr[b], e1 = bptr[b + 1];
    int nb0 = b * NB;

    for (int i = t; i < NB; i += 256) lcnt[i] = 0;
    __syncthreads();
    for (int e = e0 + t; e < e1; e += 256) atomicAdd(&lcnt[pairs[e] >> 24], 1);
    __syncthreads();

    int v = (t < NB) ? lcnt[t] : 0;
    s[t] = v;
    __syncthreads();
    for (int off = 1; off < 256; off <<= 1) {
        int a = (t >= off) ? s[t - off] : 0;
        __syncthreads();
        s[t] += a;
        __syncthreads();
    }
    if (t < NB) {
        int node = nb0 + t;
        if (node < N_NODES) {
            int excl = s[t] - v;
            lofs[t] = excl;
            row_ptr[node] = e0 + excl;
            cnt[node] = v;
            inv[node] = 1.0f / fmaxf((float)v, 1.0f);
        }
        lcnt[t] = 0;   // reuse as fill cursor
    }
    __syncthreads();
    for (int e = e0 + t; e < e1; e += 256) {
        u32 p = pairs[e];
        int dl = (int)(p >> 24);
        int pos = atomicAdd(&lcnt[dl], 1);
        csr_src[e0 + lofs[dl] + pos] = (int)(p & 0xFFFFFFu);
    }
}

// ---------------- f32 -> f16 conversion (4 elems/thread) ----------------
__global__ void tof16_kernel(const float* __restrict__ in, u16* __restrict__ outh, int n4) {
    int i = blockIdx.x * blockDim.x + threadIdx.x;
    if (i < n4) {
        float4 v = reinterpret_cast<const float4*>(in)[i];
        union { f16 h[4]; uint2 u; } cv;
        cv.h[0] = (f16)v.x; cv.h[1] = (f16)v.y; cv.h[2] = (f16)v.z; cv.h[3] = (f16)v.w;
        reinterpret_cast<uint2*>(outh)[i] = cv.u;
    }
}

// ---------------- precompute MFMA B-fragments for all 3 layers (verified layout) -----------
__global__ void prep_bfrag(const float* __restrict__ Wl0, const float* __restrict__ Wr0,
                           const float* __restrict__ Wl1, const float* __restrict__ Wr1,
                           const float* __restrict__ Wl2, const float* __restrict__ Wr2,
                           uint4* __restrict__ Bfrag) {
    int idx = blockIdx.x * blockDim.x + threadIdx.x;
    if (idx >= 3 * 16 * 64) return;
    int layer = idx >> 10, r = idx & 1023, f = r >> 6, l = r & 63;
    const float* Wl = layer == 0 ? Wl0 : layer == 1 ? Wl1 : Wl2;
    const float* Wr = layer == 0 ? Wr0 : layer == 1 ? Wr1 : Wr2;
    int ktg = f >> 2, nt = f & 3;
    const float* W = (ktg & 2) ? Wr : Wl;
    int o = nt * 16 + (l & 15);
    int k = (ktg & 1) * 32 + (l >> 4) * 8;
    const float* s = W + o * 64 + k;
    float4 v0 = *reinterpret_cast<const float4*>(s);
    float4 v1 = *reinterpret_cast<const float4*>(s + 4);
    union { f16x8 h; uint4 u; } cv;
    cv.h[0] = (f16)v0.x; cv.h[1] = (f16)v0.y; cv.h[2] = (f16)v0.z; cv.h[3] = (f16)v0.w;
    cv.h[4] = (f16)v1.x; cv.h[5] = (f16)v1.y; cv.h[6] = (f16)v1.z; cv.h[7] = (f16)v1.w;
    Bfrag[idx] = cv.u;
}

__device__ __forceinline__ void add8(float* va, uint4 r) {
    union { uint4 u; f16x8 h; } cv; cv.u = r;
    #pragma unroll
    for (int e = 0; e < 8; ++e) va[e] += (float)cv.h[e];
}

// ---------------- fused SAGE layer (MFMA, barrier-free, 8 nodes/wave) ----------------------
// Measured optimum of the design sweep: nodes/wave {16:41.2, 8:39.8, 4:47.1 us},
// unroll {4:best, 8:-22%}, dual-slot (spill), degree-sort (-7% locality loss).
// 256 threads = 4 waves; wave w owns 8 nodes (subgroup sg owns node base+sg), identity
// order (preserves L2 locality). Unroll-4 unconditional loads; 32 rows in flight/wave.
__global__ __launch_bounds__(256, 8) void sage_layer(
    const u16* __restrict__ hh,        // f16 features [N][64]
    const int* __restrict__ row_ptr, const int* __restrict__ cnt,
    const int* __restrict__ csr_src, const float* __restrict__ inv,
    const uint4* __restrict__ Bfrag,   // 16 fragments x 64 lanes (this layer)
    const float* __restrict__ bvec,
    float* __restrict__ outf,          // f32 output (nullptr to skip)
    u16* __restrict__ outh,            // f16 output (nullptr to skip)
    int relu)
{
    __shared__ u16 Atile[4][8][128];       // per-wave swizzled A, rows 0..7 only

    int t = threadIdx.x;
    int w    = t >> 6;
    int lane = t & 63;
    int j8   = lane & 7;    // channel octet within row
    int sg   = lane >> 3;   // subgroup 0..7 = node within wave
    const uint4* rows = reinterpret_cast<const uint4*>(hh);   // 8 x uint4 per node

    int base = blockIdx.x * 32 + w * 8;

    float bias[4];
    #pragma unroll
    for (int nt = 0; nt < 4; ++nt) bias[nt] = bvec[nt * 16 + (lane & 15)];

    // ---- gather: subgroup sg accumulates node base+sg ----
    {
        int n = sg;
        int node = base + n;
        bool valid = node < N_NODES;
        int nodec = valid ? node : N_NODES - 1;
        uint4 selfrow = rows[nodec * 8 + j8];       // in flight during gather
        int s0 = row_ptr[nodec];
        int c  = valid ? cnt[nodec] : 0;
        float va[8] = {0.f,0.f,0.f,0.f,0.f,0.f,0.f,0.f};
        int j = 0;
        for (; j + 4 <= c; j += 4) {
            int i0 = csr_src[s0 + j];
            int i1 = csr_src[s0 + j + 1];
            int i2 = csr_src[s0 + j + 2];
            int i3 = csr_src[s0 + j + 3];
            uint4 r0 = rows[i0 * 8 + j8];
            uint4 r1 = rows[i1 * 8 + j8];
            uint4 r2 = rows[i2 * 8 + j8];
            uint4 r3 = rows[i3 * 8 + j8];
            add8(va, r0); add8(va, r1); add8(va, r2); add8(va, r3);
        }
        for (; j < c; ++j) {
            add8(va, rows[csr_src[s0 + j] * 8 + j8]);
        }
        float sc = inv[nodec];
        union { f16x8 h; uint4 u; } mv;
        #pragma unroll
        for (int e = 0; e < 8; ++e) mv.h[e] = (f16)(va[e] * sc);
        int chunk = j8 ^ n;            // n == n&7
        if (valid) {
            *reinterpret_cast<uint4*>(&Atile[w][n][chunk * 8]) = mv.u;         // mean, k 0..63
            *reinterpret_cast<uint4*>(&Atile[w][n][64 + chunk * 8]) = selfrow; // self, k 64..127
        }
    }

    // ---- fragment reads + 16 MFMAs (B straight from global) ----
    // A row index = lane&15; only rows 0..7 are real (row bit 3 set -> read row&7's
    // data harmlessly; its C rows 8..15 are never stored).
    f32x4 acc[4] = {};
    int row = lane & 15, kg = lane >> 4;
    int rowc = row & 7;                // clamp into the 8 real rows (safe: C rows >=8 unused)
    #pragma unroll
    for (int ktg = 0; ktg < 4; ++ktg) {
        int idx16 = ktg * 4 + kg;
        int swz = (idx16 & 8) | ((idx16 & 7) ^ (rowc & 7));
        uint4 a = *reinterpret_cast<const uint4*>(&Atile[w][rowc][swz * 8]);
        union { uint4 u; f16x8 h; } av; av.u = a;
        #pragma unroll
        for (int nt = 0; nt < 4; ++nt) {
            union { uint4 u; f16x8 h; } bv; bv.u = Bfrag[(ktg * 4 + nt) * 64 + lane];
            acc[nt] = __builtin_amdgcn_mfma_f32_16x16x32_f16(av.h, bv.h, acc[nt], 0, 0, 0);
        }
    }

    // ---- epilogue: bias (+ReLU), stores. C: col=lane&15, row=(lane>>4)*4+reg ----
    // Only C rows 0..7 (kg<2) are real nodes.
    #pragma unroll
    for (int nt = 0; nt < 4; ++nt) {
        int o = nt * 16 + (lane & 15);
        #pragma unroll
        for (int r = 0; r < 4; ++r) {
            int n = kg * 4 + r;
            int node = base + n;
            if (n < 8 && node < N_NODES) {
                float vout = acc[nt][r] + bias[nt];
                if (relu) vout = fmaxf(vout, 0.f);
                if (outf) outf[node * 64 + o] = vout;
                if (outh) {
                    union { f16 h; u16 u; } cv; cv.h = (f16)vout;
                    outh[node * 64 + o] = cv.u;
                }
            }
        }
    }
}

extern "C" void kernel_launch(void* const* d_in, const int* in_sizes, int n_in,
                              void* d_out, int out_size, void* d_ws, size_t ws_size,
                              hipStream_t stream) {
    const float* x   = (const float*)d_in[0];
    const int*   ei  = (const int*)d_in[1];
    const int*   src = ei;
    const int*   dst = ei + N_EDGES;
    const float* Wl0 = (const float*)d_in[2];
    const float* Wr0 = (const float*)d_in[3];
    const float* b0  = (const float*)d_in[4];
    const float* Wl1 = (const float*)d_in[5];
    const float* Wr1 = (const float*)d_in[6];
    const float* b1  = (const float*)d_in[7];
    const float* Wl2 = (const float*)d_in[8];
    const float* Wr2 = (const float*)d_in[9];
    const float* b2  = (const float*)d_in[10];
    float* out = (float*)d_out;

    // ---- workspace layout (256B-aligned regions) ----
    char* p = (char*)d_ws;
    auto take = [&](size_t bytes) { char* r = p; p += (bytes + 255) & ~(size_t)255; return r; };
    int*   hist    = (int*)take((size_t)NCHUNK * NBUCKETS * 4);
    int*   btot    = (int*)take((size_t)NBUCKETS * 4);
    int*   bptr    = (int*)take((size_t)(NBUCKETS + 1) * 4);
    u32*   pairs   = (u32*)take((size_t)N_EDGES * 4);
    int*   csr_src = (int*)take((size_t)N_EDGES * 4);
    int*   row_ptr = (int*)take((size_t)N_NODES * 4);
    int*   cnt     = (int*)take((size_t)N_NODES * 4);
    float* inv     = (float*)take((size_t)N_NODES * 4);
    uint4* Bfrag   = (uint4*)take((size_t)3 * 16 * 64 * 16);
    u16*   xh      = (u16*)take((size_t)N_NODES * D * 2);
    u16*   h0h     = (u16*)take((size_t)N_NODES * D * 2);
    u16*   h1h     = (u16*)take((size_t)N_NODES * D * 2);

    const int BLK = 256;
    const int conv_grid  = (N_NODES * D / 4 + BLK - 1) / BLK;
    const int layer_grid = (N_NODES + 31) / 32;    // 32 nodes per block (8/wave)
    const int bgrid      = (NBUCKETS + BLK - 1) / BLK;

    // ---- deterministic bucketed partition + CSR (zero global atomics) ----
    hist_kernel<<<NCHUNK, PBLK, 0, stream>>>(dst, hist);
    colsum_kernel<<<bgrid, BLK, 0, stream>>>(hist, btot);
    bscan_kernel<<<1, 1024, 0, stream>>>(btot, bptr);
    rebase_kernel<<<bgrid, BLK, 0, stream>>>(hist, bptr);
    part_kernel<<<NCHUNK, PBLK, 0, stream>>>(src, dst, hist, pairs);
    local_csr_kernel<<<NBUCKETS, BLK, 0, stream>>>(pairs, bptr, row_ptr, cnt, inv, csr_src);
    tof16_kernel<<<conv_grid, BLK, 0, stream>>>(x, xh, N_NODES * D / 4);
    prep_bfrag<<<(3 * 1024 + BLK - 1) / BLK, BLK, 0, stream>>>(Wl0, Wr0, Wl1, Wr1, Wl2, Wr2, Bfrag);

    // ---- 3 fused layers (intermediates are f16-only) ----
    sage_layer<<<layer_grid, BLK, 0, stream>>>(xh,  row_ptr, cnt, csr_src, inv, Bfrag,        b0, nullptr, h0h, 1);
    sage_layer<<<layer_grid, BLK, 0, stream>>>(h0h, row_ptr, cnt, csr_src, inv, Bfrag + 1024, b1, nullptr, h1h, 1);
    sage_layer<<<layer_grid, BLK, 0, stream>>>(h1h, row_ptr, cnt, csr_src, inv, Bfrag + 2048, b2, out, nullptr, 0);
}